// Round 12
// baseline (1299.031 us; speedup 1.0000x reference)
//
#include <hip/hip_runtime.h>
#include <math.h>

// Problem constants
#define BB   8
#define NN   1024
#define DIN  768
#define DD   384
#define LL   6
#define HH   12
#define HDD  32
#define MM   (BB*NN)        // 8192 rows
#define EPSF 1e-5f

typedef __attribute__((ext_vector_type(8))) short short8;   // 8 bf16 (4 VGPRs)
typedef __attribute__((ext_vector_type(4))) float f32x4;    // MFMA acc

__device__ __forceinline__ unsigned short f2b(float f) {    // RNE fp32->bf16
    unsigned int u = __builtin_bit_cast(unsigned int, f);
    u = (u + 0x7fffu + ((u >> 16) & 1u)) >> 16;
    return (unsigned short)u;
}
__device__ __forceinline__ float b2f(unsigned short h) {
    return __builtin_bit_cast(float, ((unsigned int)h) << 16);
}

// ---------------------------------------------------------------------------
// Bool-mask normalization (layout auto-detected; see round-2 note).
// ---------------------------------------------------------------------------
__global__ __launch_bounds__(1024) void cvt_mask_k(const void* __restrict__ src,
                                                   int n, int* __restrict__ dst)
{
    __shared__ int flag;
    if (threadIdx.x == 0) flag = 0;
    __syncthreads();
    const int* si = (const int*)src;
    int nq = n >> 2;
    int any = 0;
    for (int i = threadIdx.x; i < nq; i += blockDim.x) any |= si[i] & ~1;
    if (any) atomicOr(&flag, 1);
    __syncthreads();
    if (flag) {
        const unsigned char* sb = (const unsigned char*)src;
        for (int i = threadIdx.x; i < n; i += blockDim.x) dst[i] = sb[i];
    } else {
        for (int i = threadIdx.x; i < n; i += blockDim.x) dst[i] = si[i];
    }
}

// ---------------------------------------------------------------------------
// fp32 -> bf16 hi/lo split, vectorized (for the full-precision GEMM inputs)
// ---------------------------------------------------------------------------
__global__ __launch_bounds__(256) void split_k(const float* __restrict__ X,
                                               unsigned short* __restrict__ Xh,
                                               unsigned short* __restrict__ Xl,
                                               int n4)
{
    int i = blockIdx.x * 256 + threadIdx.x;
    int stride = gridDim.x * 256;
    for (; i < n4; i += stride) {
        float4 v = ((const float4*)X)[i];
        ushort4 h4, l4;
        #pragma unroll
        for (int e = 0; e < 4; ++e) {
            float f = ((const float*)&v)[e];
            unsigned short hi = f2b(f);
            ((unsigned short*)&h4)[e] = hi;
            ((unsigned short*)&l4)[e] = f2b(f - b2f(hi));
        }
        ((ushort4*)Xh)[i] = h4;
        ((ushort4*)Xl)[i] = l4;
    }
}

// ---------------------------------------------------------------------------
// Per-(b, key-tile-of-64) min/max of unmasked sequence ids (for tile skipping)
// ---------------------------------------------------------------------------
__global__ __launch_bounds__(64) void kminmax_k(const int* __restrict__ sids,
                                                const int* __restrict__ smask,
                                                int2* __restrict__ kmm)
{
    int e = blockIdx.x;            // 0..127 : b*16 + kt
    int b = e >> 4, kt = e & 15;
    int lane = threadIdx.x;
    int kk = b * NN + kt * 64 + lane;
    int s = sids[kk];
    int msk = smask[kk];
    int mn = msk ? 0x7fffffff : s;
    int mx = msk ? (int)0x80000000 : s;
    #pragma unroll
    for (int off = 32; off; off >>= 1) {
        mn = min(mn, __shfl_xor(mn, off));
        mx = max(mx, __shfl_xor(mx, off));
    }
    if (lane == 0) kmm[e] = make_int2(mn, mx);
}

// ---------------------------------------------------------------------------
// Per-(b,h) mean of V over all N keys (uniform-attention output for globally
// masked query rows — reference semantics of softmax over an all-min row).
// ---------------------------------------------------------------------------
__global__ __launch_bounds__(256) void vmean_k(const unsigned short* __restrict__ qkv,
                                               unsigned short* __restrict__ vmean)
{
    __shared__ float part[8][32];
    int bh = blockIdx.x;            // 0..95
    int b = bh / HH, h = bh % HH;
    int d = threadIdx.x & 31, grp = threadIdx.x >> 5;
    const unsigned short* vp = qkv + (size_t)(b * NN + grp * 128) * (3 * DD)
                                   + 2 * DD + h * HDD + d;
    float s = 0.f;
    for (int n = 0; n < 128; ++n)
        s += b2f(vp[(size_t)n * 3 * DD]);
    part[grp][d] = s;
    __syncthreads();
    if (grp == 0) {
        float t = 0.f;
        #pragma unroll
        for (int g2 = 0; g2 < 8; ++g2) t += part[g2][d];
        vmean[bh * HDD + d] = f2b(t * (1.0f / NN));
    }
}

// ---------------------------------------------------------------------------
// Weight transpose+cast: W fp32 [K][N] -> Wt bf16 [N][K]; one layer per blockIdx.z
// ---------------------------------------------------------------------------
__global__ __launch_bounds__(256) void tcast_k(const float* __restrict__ W,
                                               unsigned short* __restrict__ Wt,
                                               int K, int N)
{
    __shared__ float tile[32][33];
    const size_t lstr = (size_t)K * N;
    const float* Wl = W + blockIdx.z * lstr;
    unsigned short* Wtl = Wt + blockIdx.z * lstr;
    int k0 = blockIdx.x * 32, n0 = blockIdx.y * 32;
    int tx = threadIdx.x & 31, ty = threadIdx.x >> 5;      // ty 0..7
    #pragma unroll
    for (int r = 0; r < 32; r += 8)
        tile[ty + r][tx] = Wl[(size_t)(k0 + ty + r) * N + n0 + tx];
    __syncthreads();
    #pragma unroll
    for (int r = 0; r < 32; r += 8)
        Wtl[(size_t)(n0 + ty + r) * K + k0 + tx] = f2b(tile[tx][ty + r]);
}

// ---------------------------------------------------------------------------
// Weight transpose + hi/lo split: W fp32 [K][N] -> WT_hi/WT_lo bf16 [N][K].
// ---------------------------------------------------------------------------
__global__ __launch_bounds__(256) void tcast2_k(const float* __restrict__ W,
                                                unsigned short* __restrict__ WTh,
                                                unsigned short* __restrict__ WTl,
                                                int K, int N)
{
    __shared__ float tile[32][33];
    int k0 = blockIdx.x * 32, n0 = blockIdx.y * 32;
    int tx = threadIdx.x & 31, ty = threadIdx.x >> 5;      // ty 0..7
    #pragma unroll
    for (int r = 0; r < 32; r += 8)
        tile[ty + r][tx] = W[(size_t)(k0 + ty + r) * N + n0 + tx];
    __syncthreads();
    #pragma unroll
    for (int r = 0; r < 32; r += 8) {
        float v = tile[tx][ty + r];
        unsigned short hi = f2b(v);
        unsigned short lo = f2b(v - b2f(hi));
        size_t idx = (size_t)(n0 + ty + r) * K + k0 + tx;
        WTh[idx] = hi;
        WTl[idx] = lo;
    }
}

// ---------------------------------------------------------------------------
// Split-bf16 (bf16x3) MFMA GEMM for the full-scale fp32 paths (embed, pproj).
// Tile 128x64, BK=32, 4 waves (2x2: 64 rows x 32 cols each), 4x2 frags.
// EPI: 0 = bias -> fp32 out ; 1 = embed(bias, mask_token, pos-embeds) -> fp32
// ---------------------------------------------------------------------------
template <int EPI>
__global__ __launch_bounds__(256) void sgemm_k(
    const unsigned short* __restrict__ Agh, const unsigned short* __restrict__ Agl,
    const unsigned short* __restrict__ WTh, const unsigned short* __restrict__ WTl,
    const float* __restrict__ bias, float* __restrict__ out,
    int K, int NO,
    const int* __restrict__ tmask, const int* __restrict__ hids,
    const int* __restrict__ wids, const float* __restrict__ mtok,
    const float* __restrict__ hemb, const float* __restrict__ wemb)
{
    __shared__ unsigned short Ah[128][40];
    __shared__ unsigned short Al[128][40];
    __shared__ unsigned short Bh[64][40];
    __shared__ unsigned short Bl[64][40];

    const int tid  = threadIdx.x;
    const int lane = tid & 63;
    const int wave = tid >> 6;
    const int wr = wave >> 1, wc = wave & 1;
    const int rowBase = blockIdx.x * 128;
    const int colBase = blockIdx.y * 64;
    const int rr = lane & 15;
    const int kr = (lane >> 4) * 8;

    f32x4 acc[4][2] = {};

    for (int k0 = 0; k0 < K; k0 += 32) {
        #pragma unroll
        for (int i = 0; i < 2; ++i) {
            int s   = tid + i * 256;       // 0..511
            int row = s >> 2;              // 0..127
            int seg = (s & 3) * 8;
            size_t gi = (size_t)(rowBase + row) * K + k0 + seg;
            *(short8*)&Ah[row][seg] = *(const short8*)&Agh[gi];
            *(short8*)&Al[row][seg] = *(const short8*)&Agl[gi];
        }
        {
            int row = tid >> 2;            // 0..63
            int seg = (tid & 3) * 8;
            size_t gi = (size_t)(colBase + row) * K + k0 + seg;
            *(short8*)&Bh[row][seg] = *(const short8*)&WTh[gi];
            *(short8*)&Bl[row][seg] = *(const short8*)&WTl[gi];
        }
        __syncthreads();

        short8 ah[4], al[4], bh2[2], bl2[2];
        #pragma unroll
        for (int i = 0; i < 4; ++i) {
            ah[i] = *(const short8*)&Ah[wr * 64 + i * 16 + rr][kr];
            al[i] = *(const short8*)&Al[wr * 64 + i * 16 + rr][kr];
        }
        #pragma unroll
        for (int j = 0; j < 2; ++j) {
            bh2[j] = *(const short8*)&Bh[wc * 32 + j * 16 + rr][kr];
            bl2[j] = *(const short8*)&Bl[wc * 32 + j * 16 + rr][kr];
        }
        #pragma unroll
        for (int i = 0; i < 4; ++i)
            #pragma unroll
            for (int j = 0; j < 2; ++j) {
                acc[i][j] = __builtin_amdgcn_mfma_f32_16x16x32_bf16(
                    al[i], bh2[j], acc[i][j], 0, 0, 0);
                acc[i][j] = __builtin_amdgcn_mfma_f32_16x16x32_bf16(
                    ah[i], bl2[j], acc[i][j], 0, 0, 0);
                acc[i][j] = __builtin_amdgcn_mfma_f32_16x16x32_bf16(
                    ah[i], bh2[j], acc[i][j], 0, 0, 0);
            }
        __syncthreads();
    }

    const int colq = colBase + wc * 32 + rr;
    const int rq0  = rowBase + wr * 64 + (lane >> 4) * 4;
    #pragma unroll
    for (int j = 0; j < 2; ++j) {
        const int col = colq + j * 16;
        const float bi = bias[col];
        #pragma unroll
        for (int i = 0; i < 4; ++i) {
            #pragma unroll
            for (int r = 0; r < 4; ++r) {
                const int row = rq0 + i * 16 + r;
                float v = acc[i][j][r] + bi;
                if constexpr (EPI == 1) {      // embed epilogue
                    float xv = tmask[row] ? mtok[col] : v;
                    out[(size_t)row * NO + col] = xv
                        + hemb[(size_t)hids[row] * DD + col]
                        + wemb[(size_t)wids[row] * DD + col];
                } else {
                    out[(size_t)row * NO + col] = v;
                }
            }
        }
    }
}

// ---------------------------------------------------------------------------
// bf16 MFMA GEMM: C[M x NO] = A[M x K] @ W[K x NO]
// Tile 128x128, BK=32, 4 waves (2x2), 64x64/wave = 4x4 frags of 16x16x32.
// EPI: 0 = bias -> bf16 out ; 2 = h += ls*(acc+bias) (fp32) ; 3 = gelu -> bf16
// ---------------------------------------------------------------------------
template <int EPI>
__global__ __launch_bounds__(256) void bgemm_k(
    const unsigned short* __restrict__ A, const unsigned short* __restrict__ Wt,
    const float* __restrict__ bias, void* __restrict__ out,
    int K, int NO, const float* __restrict__ ls)
{
    __shared__ unsigned short As[128][40];
    __shared__ unsigned short Bs[128][40];

    const int tid  = threadIdx.x;
    const int lane = tid & 63;
    const int wave = tid >> 6;
    const int wr = wave >> 1, wc = wave & 1;
    const int rowBase = blockIdx.x * 128;
    const int colBase = blockIdx.y * 128;
    const int rr = lane & 15;
    const int kr = (lane >> 4) * 8;

    f32x4 acc[4][4] = {};

    for (int k0 = 0; k0 < K; k0 += 32) {
        #pragma unroll
        for (int i = 0; i < 2; ++i) {
            int s   = tid + i * 256;       // 0..511
            int row = s >> 2;              // 0..127
            int seg = (s & 3) * 8;         // bf16 offset 0,8,16,24
            *(short8*)&As[row][seg] =
                *(const short8*)&A[(size_t)(rowBase + row) * K + k0 + seg];
            *(short8*)&Bs[row][seg] =
                *(const short8*)&Wt[(size_t)(colBase + row) * K + k0 + seg];
        }
        __syncthreads();

        short8 af[4], bfr[4];
        #pragma unroll
        for (int i = 0; i < 4; ++i)
            af[i] = *(const short8*)&As[wr * 64 + i * 16 + rr][kr];
        #pragma unroll
        for (int j = 0; j < 4; ++j)
            bfr[j] = *(const short8*)&Bs[wc * 64 + j * 16 + rr][kr];
        #pragma unroll
        for (int i = 0; i < 4; ++i)
            #pragma unroll
            for (int j = 0; j < 4; ++j)
                acc[i][j] = __builtin_amdgcn_mfma_f32_16x16x32_bf16(
                    af[i], bfr[j], acc[i][j], 0, 0, 0);
        __syncthreads();
    }

    const int colq = colBase + wc * 64 + rr;
    const int rq0  = rowBase + wr * 64 + (lane >> 4) * 4;
    #pragma unroll
    for (int j = 0; j < 4; ++j) {
        const int col = colq + j * 16;
        const float bi = bias[col];
        float lsv = 0.f;
        if constexpr (EPI == 2) lsv = ls[col];
        #pragma unroll
        for (int i = 0; i < 4; ++i) {
            #pragma unroll
            for (int r = 0; r < 4; ++r) {
                const int row = rq0 + i * 16 + r;
                float v = acc[i][j][r] + bi;
                if constexpr (EPI == 0) {
                    ((unsigned short*)out)[(size_t)row * NO + col] = f2b(v);
                } else if constexpr (EPI == 2) {
                    float* hp = (float*)out + (size_t)row * NO + col;
                    *hp += lsv * v;
                } else {  // gelu (exact) -> bf16
                    float g = 0.5f * v * (1.0f + erff(v * 0.70710678118654752f));
                    ((unsigned short*)out)[(size_t)row * NO + col] = f2b(g);
                }
            }
        }
    }
}

// ---------------------------------------------------------------------------
// Split-K bf16 MFMA GEMM (for fc2: N=384 -> only 192 blocks un-split, 0.75/CU,
// latency-bound at 48 serial k-steps — round-11 counters: Occ 7.4%, Mfma 6.6%).
// Grid z = 4 K-splits; each block computes a K/4 partial and atomicAdds
// ls*(partial [+ bias on split 0]) into fp32 h. Associativity-only reorder.
// ---------------------------------------------------------------------------
__global__ __launch_bounds__(256) void bgemm_sk_k(
    const unsigned short* __restrict__ A, const unsigned short* __restrict__ Wt,
    const float* __restrict__ bias, float* __restrict__ h,
    int K, int NO, const float* __restrict__ ls)
{
    __shared__ unsigned short As[128][40];
    __shared__ unsigned short Bs[128][40];

    const int tid  = threadIdx.x;
    const int lane = tid & 63;
    const int wave = tid >> 6;
    const int wr = wave >> 1, wc = wave & 1;
    const int rowBase = blockIdx.x * 128;
    const int colBase = blockIdx.y * 128;
    const int ks = blockIdx.z;           // 0..3
    const int kc = K >> 2;               // K/4
    const int rr = lane & 15;
    const int kr = (lane >> 4) * 8;

    f32x4 acc[4][4] = {};

    for (int k0 = ks * kc; k0 < (ks + 1) * kc; k0 += 32) {
        #pragma unroll
        for (int i = 0; i < 2; ++i) {
            int s   = tid + i * 256;
            int row = s >> 2;
            int seg = (s & 3) * 8;
            *(short8*)&As[row][seg] =
                *(const short8*)&A[(size_t)(rowBase + row) * K + k0 + seg];
            *(short8*)&Bs[row][seg] =
                *(const short8*)&Wt[(size_t)(colBase + row) * K + k0 + seg];
        }
        __syncthreads();

        short8 af[4], bfr[4];
        #pragma unroll
        for (int i = 0; i < 4; ++i)
            af[i] = *(const short8*)&As[wr * 64 + i * 16 + rr][kr];
        #pragma unroll
        for (int j = 0; j < 4; ++j)
            bfr[j] = *(const short8*)&Bs[wc * 64 + j * 16 + rr][kr];
        #pragma unroll
        for (int i = 0; i < 4; ++i)
            #pragma unroll
            for (int j = 0; j < 4; ++j)
                acc[i][j] = __builtin_amdgcn_mfma_f32_16x16x32_bf16(
                    af[i], bfr[j], acc[i][j], 0, 0, 0);
        __syncthreads();
    }

    const int colq = colBase + wc * 64 + rr;
    const int rq0  = rowBase + wr * 64 + (lane >> 4) * 4;
    #pragma unroll
    for (int j = 0; j < 4; ++j) {
        const int col = colq + j * 16;
        const float bi = (ks == 0) ? bias[col] : 0.f;
        const float lsv = ls[col];
        #pragma unroll
        for (int i = 0; i < 4; ++i) {
            #pragma unroll
            for (int r = 0; r < 4; ++r) {
                const int row = rq0 + i * 16 + r;
                atomicAdd(&h[(size_t)row * NO + col], lsv * (acc[i][j][r] + bi));
            }
        }
    }
}

// ---------------------------------------------------------------------------
// LayerNorm: one wave per row, float2-vectorized.
// OUT: 1 = bf16 out ; 2 = bf16 hi/lo pair out (for the split GEMM input)
// ---------------------------------------------------------------------------
template <int OUT>
__global__ __launch_bounds__(256) void ln_k(
    const float* __restrict__ X, const float* __restrict__ w,
    const float* __restrict__ b, void* __restrict__ Y, void* __restrict__ Yl)
{
    int row  = blockIdx.x * 4 + (threadIdx.x >> 6);
    int lane = threadIdx.x & 63;
    const float* xr = X + (size_t)row * DD;

    float2 x2[3];
    #pragma unroll
    for (int j = 0; j < 3; ++j)
        x2[j] = *(const float2*)&xr[2 * (lane + 64 * j)];

    float s = 0.f;
    #pragma unroll
    for (int j = 0; j < 3; ++j) s += x2[j].x + x2[j].y;
    #pragma unroll
    for (int off = 32; off > 0; off >>= 1) s += __shfl_xor(s, off);
    float mu = s * (1.0f / 384.0f);

    float v = 0.f;
    #pragma unroll
    for (int j = 0; j < 3; ++j) {
        float d0 = x2[j].x - mu, d1 = x2[j].y - mu;
        v += d0 * d0 + d1 * d1;
    }
    #pragma unroll
    for (int off = 32; off > 0; off >>= 1) v += __shfl_xor(v, off);
    float rstd = rsqrtf(v * (1.0f / 384.0f) + EPSF);

    #pragma unroll
    for (int j = 0; j < 3; ++j) {
        int c = 2 * (lane + 64 * j);
        float2 w2 = *(const float2*)&w[c];
        float2 b2 = *(const float2*)&b[c];
        float y0 = (x2[j].x - mu) * rstd * w2.x + b2.x;
        float y1 = (x2[j].y - mu) * rstd * w2.y + b2.y;
        unsigned short h0 = f2b(y0), h1 = f2b(y1);
        *(ushort2*)&((unsigned short*)Y)[(size_t)row * DD + c] = make_ushort2(h0, h1);
        if constexpr (OUT == 2) {
            unsigned short l0 = f2b(y0 - b2f(h0)), l1 = f2b(y1 - b2f(h1));
            *(ushort2*)&((unsigned short*)Yl)[(size_t)row * DD + c] = make_ushort2(l0, l1);
        }
    }
}

// ---------------------------------------------------------------------------
// MFMA flash attention with block-diagonal tile skipping (see round-7 notes).
// ---------------------------------------------------------------------------
__global__ __launch_bounds__(256) void attn_mfma_k(
    const unsigned short* __restrict__ qkv, const int* __restrict__ sids,
    const int* __restrict__ smask, const int2* __restrict__ kmm,
    const unsigned short* __restrict__ vmean, unsigned short* __restrict__ out)
{
    __shared__ unsigned short Vt[32][72];     // [d][key], pad 64->72
    __shared__ int ck[64];
    __shared__ unsigned short P[4][16][64];   // per-wave P tile (XOR-swizzled cols)
    __shared__ int qmn[4], qmx[4];

    const int tid  = threadIdx.x;
    const int lane = tid & 63;
    const int wave = tid >> 6;
    const int g = lane >> 4;                  // 0..3
    const int c = lane & 15;

    const int bh = blockIdx.x >> 4;           // 16 q-tiles per (b,h)
    const int qt = blockIdx.x & 15;
    const int b = bh / HH, h = bh % HH;
    const int q0w = qt * 64 + wave * 16;
    const size_t qrow = 3 * DD;               // 1152

    const short8 qf = *(const short8*)&qkv[(size_t)(b * NN + q0w + c) * qrow + h * HDD + g * 8];

    int cq[4];
    #pragma unroll
    for (int r = 0; r < 4; ++r) {
        int qq = b * NN + q0w + 4 * g + r;
        cq[r] = smask[qq] ? -2 : sids[qq];
    }

    {
        int lmin = 0x7fffffff, lmax = (int)0x80000000;
        #pragma unroll
        for (int r = 0; r < 4; ++r) {
            if (cq[r] != -2) { lmin = min(lmin, cq[r]); lmax = max(lmax, cq[r]); }
        }
        #pragma unroll
        for (int off = 32; off; off >>= 1) {
            lmin = min(lmin, __shfl_xor(lmin, off));
            lmax = max(lmax, __shfl_xor(lmax, off));
        }
        if (lane == 0) { qmn[wave] = lmin; qmx[wave] = lmax; }
    }
    __syncthreads();
    int qminb = min(min(qmn[0], qmn[1]), min(qmn[2], qmn[3]));
    int qmaxb = max(max(qmx[0], qmx[1]), max(qmx[2], qmx[3]));

    float m[4] = {-INFINITY, -INFINITY, -INFINITY, -INFINITY};
    float l[4] = {};
    f32x4 o[2] = {};
    const f32x4 zero = {};
    const float scale = 0.17677669529663687f; // HD^-0.5
    const float FMIN = -3.402823466e38f;

    for (int kt = 0; kt < NN / 64; ++kt) {
        const int2 kr2 = kmm[(b << 4) + kt];
        if (kr2.x > qmaxb || kr2.y < qminb) continue;   // block-uniform skip

        const int kb = kt * 64;
        {
            int key = tid & 63;
            int d8  = (tid >> 6) * 8;
            short8 v = *(const short8*)&qkv[(size_t)(b * NN + kb + key) * qrow + 2 * DD + h * HDD + d8];
            #pragma unroll
            for (int e = 0; e < 8; ++e)
                Vt[d8 + e][key] = (unsigned short)v[e];
            if (tid < 64) {
                int kk = b * NN + kb + tid;
                ck[tid] = smask[kk] ? -1 : sids[kk];
            }
        }
        __syncthreads();

        f32x4 s4[4];
        #pragma unroll
        for (int j = 0; j < 4; ++j) {
            short8 kf = *(const short8*)&qkv[(size_t)(b * NN + kb + 16 * j + c) * qrow + DD + h * HDD + g * 8];
            s4[j] = __builtin_amdgcn_mfma_f32_16x16x32_bf16(qf, kf, zero, 0, 0, 0);
        }

        float pm[4] = {FMIN, FMIN, FMIN, FMIN};
        #pragma unroll
        for (int j = 0; j < 4; ++j) {
            const int ckj = ck[16 * j + c];
            #pragma unroll
            for (int r = 0; r < 4; ++r) {
                float sv = (cq[r] != ckj) ? FMIN : s4[j][r] * scale;
                s4[j][r] = sv;
                pm[r] = fmaxf(pm[r], sv);
            }
        }
        #pragma unroll
        for (int off = 1; off < 16; off <<= 1)
            #pragma unroll
            for (int r = 0; r < 4; ++r)
                pm[r] = fmaxf(pm[r], __shfl_xor(pm[r], off));

        float fac[4], psum[4];
        #pragma unroll
        for (int r = 0; r < 4; ++r) {
            float mn = fmaxf(m[r], pm[r]);
            fac[r] = __expf(m[r] - mn);
            m[r] = mn;
            psum[r] = 0.f;
        }
        #pragma unroll
        for (int j = 0; j < 4; ++j) {
            #pragma unroll
            for (int r = 0; r < 4; ++r) {
                float p = __expf(s4[j][r] - m[r]);
                psum[r] += p;
                int row  = 4 * g + r;
                int colb = (2 * (16 * j + c)) ^ ((row & 7) << 4);
                *(unsigned short*)((char*)&P[wave][row][0] + colb) = f2b(p);
            }
        }
        #pragma unroll
        for (int off = 1; off < 16; off <<= 1)
            #pragma unroll
            for (int r = 0; r < 4; ++r)
                psum[r] += __shfl_xor(psum[r], off);
        #pragma unroll
        for (int r = 0; r < 4; ++r) l[r] = l[r] * fac[r] + psum[r];

        #pragma unroll
        for (int dc = 0; dc < 2; ++dc)
            #pragma unroll
            for (int r = 0; r < 4; ++r)
                o[dc][r] *= fac[r];

        #pragma unroll
        for (int kc = 0; kc < 2; ++kc) {
            int colb = (2 * (kc * 32 + g * 8)) ^ ((c & 7) << 4);
            short8 pf = *(const short8*)((char*)&P[wave][c][0] + colb);
            #pragma unroll
            for (int dc = 0; dc < 2; ++dc) {
                short8 vf = *(const short8*)&Vt[dc * 16 + c][kc * 32 + g * 8];
                o[dc] = __builtin_amdgcn_mfma_f32_16x16x32_bf16(pf, vf, o[dc], 0, 0, 0);
            }
        }
        __syncthreads();
    }

    #pragma unroll
    for (int r = 0; r < 4; ++r) {
        unsigned short* op = &out[(size_t)(b * NN + q0w + 4 * g + r) * DD + h * HDD];
        if (cq[r] == -2) {
            #pragma unroll
            for (int dc = 0; dc < 2; ++dc)
                op[dc * 16 + c] = vmean[bh * HDD + dc * 16 + c];
        } else {
            const float inv = 1.0f / l[r];
            #pragma unroll
            for (int dc = 0; dc < 2; ++dc)
                op[dc * 16 + c] = f2b(o[dc][r] * inv);
        }
    }
}

// ---------------------------------------------------------------------------
extern "C" void kernel_launch(void* const* d_in, const int* in_sizes, int n_in,
                              void* d_out, int out_size, void* d_ws, size_t ws_size,
                              hipStream_t stream)
{
    const float* x        = (const float*)d_in[0];
    const int*   hids     = (const int*)d_in[1];
    const int*   wids     = (const int*)d_in[2];
    const void*  tmask_rw = d_in[3];
    const int*   sids     = (const int*)d_in[4];
    const void*  smask_rw = d_in[5];
    const float* embed_w  = (const float*)d_in[7];
    const float* embed_b  = (const float*)d_in[8];
    const float* h_embed  = (const float*)d_in[9];
    const float* w_embed  = (const float*)d_in[10];
    const float* mtok     = (const float*)d_in[11];
    const float* norm1_w  = (const float*)d_in[12];
    const float* norm1_b  = (const float*)d_in[13];
    const float* ls1      = (const float*)d_in[14];
    const float* qkv_w    = (const float*)d_in[15];
    const float* qkv_b    = (const float*)d_in[16];
    const float* proj_w   = (const float*)d_in[17];
    const float* proj_b   = (const float*)d_in[18];
    const float* norm2_w  = (const float*)d_in[19];
    const float* norm2_b  = (const float*)d_in[20];
    const float* fc1_w    = (const float*)d_in[21];
    const float* fc1_b    = (const float*)d_in[22];
    const float* fc2_w    = (const float*)d_in[23];
    const float* fc2_b    = (const float*)d_in[24];
    const float* ls2      = (const float*)d_in[25];
    const float* pnorm_w  = (const float*)d_in[26];
    const float* pnorm_b  = (const float*)d_in[27];
    const float* pproj_w  = (const float*)d_in[28];
    const float* pproj_b  = (const float*)d_in[29];

    const size_t MD = (size_t)MM * DD;
    float*          h    = (float*)d_ws;
    unsigned short* zb   = (unsigned short*)(h + MD);
    unsigned short* hid  = zb + MD;                 // 4*MD ushorts
    unsigned short* qkvb = hid;                     // alias (disjoint liveness)
    unsigned short* zfh  = hid;                     // alias: pnorm hi (after fc2 done)
    unsigned short* zfl  = hid + MD;                // alias: pnorm lo
    const size_t xsz = (size_t)MM * DIN;            // 6.29M
    unsigned short* xh = hid;                       // alias: dead before qkv bgemm
    unsigned short* xl = hid + xsz;
    unsigned short* wT   = hid + 4 * MD;
    const size_t qkvTsz  = (size_t)LL * 3 * DD * DD;
    const size_t projTsz = (size_t)LL * DD * DD;
    const size_t fc1Tsz  = (size_t)LL * DD * 4 * DD;
    unsigned short* qkvT = wT;
    unsigned short* projT = qkvT + qkvTsz;
    unsigned short* fc1T  = projT + projTsz;
    unsigned short* fc2T  = fc1T + fc1Tsz;
    int* tm32 = (int*)(fc2T + fc1Tsz);
    int* sm32 = tm32 + MM;
    unsigned short* vmean = (unsigned short*)(sm32 + MM);   // 96*32 bf16
    int2* kmm = (int2*)(vmean + BB * HH * HDD);             // 128 int2
    const size_t ewsz = (size_t)DIN * DD;                   // 294912
    unsigned short* ewT_hi = (unsigned short*)(kmm + BB * 16);
    unsigned short* ewT_lo = ewT_hi + ewsz;
    unsigned short* pwT_hi = ewT_lo + ewsz;
    unsigned short* pwT_lo = pwT_hi + ewsz;

    cvt_mask_k<<<1, 1024, 0, stream>>>(tmask_rw, MM, tm32);
    cvt_mask_k<<<1, 1024, 0, stream>>>(smask_rw, MM, sm32);
    kminmax_k<<<BB * 16, 64, 0, stream>>>(sids, sm32, kmm);

    dim3 t256(256);
    tcast_k<<<dim3(DD/32, 3*DD/32, LL), t256, 0, stream>>>(qkv_w, qkvT, DD, 3*DD);
    tcast_k<<<dim3(DD/32, DD/32,   LL), t256, 0, stream>>>(proj_w, projT, DD, DD);
    tcast_k<<<dim3(DD/32, 4*DD/32, LL), t256, 0, stream>>>(fc1_w, fc1T, DD, 4*DD);
    tcast_k<<<dim3(4*DD/32, DD/32, LL), t256, 0, stream>>>(fc2_w, fc2T, 4*DD, DD);
    tcast2_k<<<dim3(DIN/32, DD/32), t256, 0, stream>>>(embed_w, ewT_hi, ewT_lo, DIN, DD);
    tcast2_k<<<dim3(DD/32, DIN/32), t256, 0, stream>>>(pproj_w, pwT_hi, pwT_lo, DD, DIN);
    split_k<<<2048, t256, 0, stream>>>(x, xh, xl, (int)(xsz / 4));

    sgemm_k<1><<<dim3(MM/128, DD/64), t256, 0, stream>>>(
        xh, xl, ewT_hi, ewT_lo, embed_b, h, DIN, DD, tm32, hids, wids, mtok, h_embed, w_embed);

    for (int i = 0; i < LL; ++i) {
        ln_k<1><<<MM/4, t256, 0, stream>>>(h, norm1_w + i*DD, norm1_b + i*DD, zb, nullptr);
        bgemm_k<0><<<dim3(MM/128, 3*DD/128), t256, 0, stream>>>(
            zb, qkvT + (size_t)i*3*DD*DD, qkv_b + i*3*DD, qkvb, DD, 3*DD, nullptr);
        vmean_k<<<BB * HH, t256, 0, stream>>>(qkvb, vmean);
        attn_mfma_k<<<dim3(BB*HH*(NN/64)), t256, 0, stream>>>(
            qkvb, sids, sm32, kmm, vmean, zb);
        bgemm_k<2><<<dim3(MM/128, DD/128), t256, 0, stream>>>(
            zb, projT + (size_t)i*DD*DD, proj_b + i*DD, h, DD, DD, ls1 + i*DD);
        ln_k<1><<<MM/4, t256, 0, stream>>>(h, norm2_w + i*DD, norm2_b + i*DD, zb, nullptr);
        bgemm_k<3><<<dim3(MM/128, 4*DD/128), t256, 0, stream>>>(
            zb, fc1T + (size_t)i*DD*4*DD, fc1_b + i*4*DD, hid, DD, 4*DD, nullptr);
        // fc2 via split-K=4: 192 -> 768 blocks (was 0.75/CU, latency-bound)
        bgemm_sk_k<<<dim3(MM/128, DD/128, 4), t256, 0, stream>>>(
            hid, fc2T + (size_t)i*4*DD*DD, fc2_b + i*DD, h, 4*DD, DD, ls2 + i*DD);
    }

    ln_k<2><<<MM/4, t256, 0, stream>>>(h, pnorm_w, pnorm_b, zfh, zfl);
    sgemm_k<0><<<dim3(MM/128, DIN/64), t256, 0, stream>>>(
        zfh, zfl, pwT_hi, pwT_lo, pproj_b, (float*)d_out, DD, DIN,
        nullptr, nullptr, nullptr, nullptr, nullptr, nullptr);
}

// Round 13
// 1114.884 us; speedup vs baseline: 1.1652x; 1.1652x over previous
//
#include <hip/hip_runtime.h>
#include <math.h>

// Problem constants
#define BB   8
#define NN   1024
#define DIN  768
#define DD   384
#define LL   6
#define HH   12
#define HDD  32
#define MM   (BB*NN)        // 8192 rows
#define EPSF 1e-5f

typedef __attribute__((ext_vector_type(8))) short short8;   // 8 bf16 (4 VGPRs)
typedef __attribute__((ext_vector_type(4))) float f32x4;    // MFMA acc

__device__ __forceinline__ unsigned short f2b(float f) {    // RNE fp32->bf16
    unsigned int u = __builtin_bit_cast(unsigned int, f);
    u = (u + 0x7fffu + ((u >> 16) & 1u)) >> 16;
    return (unsigned short)u;
}
__device__ __forceinline__ float b2f(unsigned short h) {
    return __builtin_bit_cast(float, ((unsigned int)h) << 16);
}

// ---------------------------------------------------------------------------
// Bool-mask normalization (layout auto-detected; see round-2 note).
// ---------------------------------------------------------------------------
__global__ __launch_bounds__(1024) void cvt_mask_k(const void* __restrict__ src,
                                                   int n, int* __restrict__ dst)
{
    __shared__ int flag;
    if (threadIdx.x == 0) flag = 0;
    __syncthreads();
    const int* si = (const int*)src;
    int nq = n >> 2;
    int any = 0;
    for (int i = threadIdx.x; i < nq; i += blockDim.x) any |= si[i] & ~1;
    if (any) atomicOr(&flag, 1);
    __syncthreads();
    if (flag) {
        const unsigned char* sb = (const unsigned char*)src;
        for (int i = threadIdx.x; i < n; i += blockDim.x) dst[i] = sb[i];
    } else {
        for (int i = threadIdx.x; i < n; i += blockDim.x) dst[i] = si[i];
    }
}

// ---------------------------------------------------------------------------
// fp32 -> bf16 hi/lo split, vectorized (for the full-precision GEMM inputs)
// ---------------------------------------------------------------------------
__global__ __launch_bounds__(256) void split_k(const float* __restrict__ X,
                                               unsigned short* __restrict__ Xh,
                                               unsigned short* __restrict__ Xl,
                                               int n4)
{
    int i = blockIdx.x * 256 + threadIdx.x;
    int stride = gridDim.x * 256;
    for (; i < n4; i += stride) {
        float4 v = ((const float4*)X)[i];
        ushort4 h4, l4;
        #pragma unroll
        for (int e = 0; e < 4; ++e) {
            float f = ((const float*)&v)[e];
            unsigned short hi = f2b(f);
            ((unsigned short*)&h4)[e] = hi;
            ((unsigned short*)&l4)[e] = f2b(f - b2f(hi));
        }
        ((ushort4*)Xh)[i] = h4;
        ((ushort4*)Xl)[i] = l4;
    }
}

// ---------------------------------------------------------------------------
// Per-(b, key-tile-of-64) min/max of unmasked sequence ids (for tile skipping)
// ---------------------------------------------------------------------------
__global__ __launch_bounds__(64) void kminmax_k(const int* __restrict__ sids,
                                                const int* __restrict__ smask,
                                                int2* __restrict__ kmm)
{
    int e = blockIdx.x;            // 0..127 : b*16 + kt
    int b = e >> 4, kt = e & 15;
    int lane = threadIdx.x;
    int kk = b * NN + kt * 64 + lane;
    int s = sids[kk];
    int msk = smask[kk];
    int mn = msk ? 0x7fffffff : s;
    int mx = msk ? (int)0x80000000 : s;
    #pragma unroll
    for (int off = 32; off; off >>= 1) {
        mn = min(mn, __shfl_xor(mn, off));
        mx = max(mx, __shfl_xor(mx, off));
    }
    if (lane == 0) kmm[e] = make_int2(mn, mx);
}

// ---------------------------------------------------------------------------
// Per-(b,h) mean of V over all N keys (uniform-attention output for globally
// masked query rows — reference semantics of softmax over an all-min row).
// ---------------------------------------------------------------------------
__global__ __launch_bounds__(256) void vmean_k(const unsigned short* __restrict__ qkv,
                                               unsigned short* __restrict__ vmean)
{
    __shared__ float part[8][32];
    int bh = blockIdx.x;            // 0..95
    int b = bh / HH, h = bh % HH;
    int d = threadIdx.x & 31, grp = threadIdx.x >> 5;
    const unsigned short* vp = qkv + (size_t)(b * NN + grp * 128) * (3 * DD)
                                   + 2 * DD + h * HDD + d;
    float s = 0.f;
    for (int n = 0; n < 128; ++n)
        s += b2f(vp[(size_t)n * 3 * DD]);
    part[grp][d] = s;
    __syncthreads();
    if (grp == 0) {
        float t = 0.f;
        #pragma unroll
        for (int g2 = 0; g2 < 8; ++g2) t += part[g2][d];
        vmean[bh * HDD + d] = f2b(t * (1.0f / NN));
    }
}

// ---------------------------------------------------------------------------
// Weight transpose+cast: W fp32 [K][N] -> Wt bf16 [N][K]; one layer per blockIdx.z
// ---------------------------------------------------------------------------
__global__ __launch_bounds__(256) void tcast_k(const float* __restrict__ W,
                                               unsigned short* __restrict__ Wt,
                                               int K, int N)
{
    __shared__ float tile[32][33];
    const size_t lstr = (size_t)K * N;
    const float* Wl = W + blockIdx.z * lstr;
    unsigned short* Wtl = Wt + blockIdx.z * lstr;
    int k0 = blockIdx.x * 32, n0 = blockIdx.y * 32;
    int tx = threadIdx.x & 31, ty = threadIdx.x >> 5;      // ty 0..7
    #pragma unroll
    for (int r = 0; r < 32; r += 8)
        tile[ty + r][tx] = Wl[(size_t)(k0 + ty + r) * N + n0 + tx];
    __syncthreads();
    #pragma unroll
    for (int r = 0; r < 32; r += 8)
        Wtl[(size_t)(n0 + ty + r) * K + k0 + tx] = f2b(tile[tx][ty + r]);
}

// ---------------------------------------------------------------------------
// Weight transpose + hi/lo split: W fp32 [K][N] -> WT_hi/WT_lo bf16 [N][K].
// ---------------------------------------------------------------------------
__global__ __launch_bounds__(256) void tcast2_k(const float* __restrict__ W,
                                                unsigned short* __restrict__ WTh,
                                                unsigned short* __restrict__ WTl,
                                                int K, int N)
{
    __shared__ float tile[32][33];
    int k0 = blockIdx.x * 32, n0 = blockIdx.y * 32;
    int tx = threadIdx.x & 31, ty = threadIdx.x >> 5;      // ty 0..7
    #pragma unroll
    for (int r = 0; r < 32; r += 8)
        tile[ty + r][tx] = W[(size_t)(k0 + ty + r) * N + n0 + tx];
    __syncthreads();
    #pragma unroll
    for (int r = 0; r < 32; r += 8) {
        float v = tile[tx][ty + r];
        unsigned short hi = f2b(v);
        unsigned short lo = f2b(v - b2f(hi));
        size_t idx = (size_t)(n0 + ty + r) * K + k0 + tx;
        WTh[idx] = hi;
        WTl[idx] = lo;
    }
}

// ---------------------------------------------------------------------------
// Split-bf16 (bf16x3) MFMA GEMM for the full-scale fp32 paths (embed, pproj).
// Tile 128x64, BK=32, 4 waves (2x2: 64 rows x 32 cols each), 4x2 frags.
// EPI: 0 = bias -> fp32 out ; 1 = embed(bias, mask_token, pos-embeds) -> fp32
// ---------------------------------------------------------------------------
template <int EPI>
__global__ __launch_bounds__(256) void sgemm_k(
    const unsigned short* __restrict__ Agh, const unsigned short* __restrict__ Agl,
    const unsigned short* __restrict__ WTh, const unsigned short* __restrict__ WTl,
    const float* __restrict__ bias, float* __restrict__ out,
    int K, int NO,
    const int* __restrict__ tmask, const int* __restrict__ hids,
    const int* __restrict__ wids, const float* __restrict__ mtok,
    const float* __restrict__ hemb, const float* __restrict__ wemb)
{
    __shared__ unsigned short Ah[128][40];
    __shared__ unsigned short Al[128][40];
    __shared__ unsigned short Bh[64][40];
    __shared__ unsigned short Bl[64][40];

    const int tid  = threadIdx.x;
    const int lane = tid & 63;
    const int wave = tid >> 6;
    const int wr = wave >> 1, wc = wave & 1;
    const int rowBase = blockIdx.x * 128;
    const int colBase = blockIdx.y * 64;
    const int rr = lane & 15;
    const int kr = (lane >> 4) * 8;

    f32x4 acc[4][2] = {};

    for (int k0 = 0; k0 < K; k0 += 32) {
        #pragma unroll
        for (int i = 0; i < 2; ++i) {
            int s   = tid + i * 256;       // 0..511
            int row = s >> 2;              // 0..127
            int seg = (s & 3) * 8;
            size_t gi = (size_t)(rowBase + row) * K + k0 + seg;
            *(short8*)&Ah[row][seg] = *(const short8*)&Agh[gi];
            *(short8*)&Al[row][seg] = *(const short8*)&Agl[gi];
        }
        {
            int row = tid >> 2;            // 0..63
            int seg = (tid & 3) * 8;
            size_t gi = (size_t)(colBase + row) * K + k0 + seg;
            *(short8*)&Bh[row][seg] = *(const short8*)&WTh[gi];
            *(short8*)&Bl[row][seg] = *(const short8*)&WTl[gi];
        }
        __syncthreads();

        short8 ah[4], al[4], bh2[2], bl2[2];
        #pragma unroll
        for (int i = 0; i < 4; ++i) {
            ah[i] = *(const short8*)&Ah[wr * 64 + i * 16 + rr][kr];
            al[i] = *(const short8*)&Al[wr * 64 + i * 16 + rr][kr];
        }
        #pragma unroll
        for (int j = 0; j < 2; ++j) {
            bh2[j] = *(const short8*)&Bh[wc * 32 + j * 16 + rr][kr];
            bl2[j] = *(const short8*)&Bl[wc * 32 + j * 16 + rr][kr];
        }
        #pragma unroll
        for (int i = 0; i < 4; ++i)
            #pragma unroll
            for (int j = 0; j < 2; ++j) {
                acc[i][j] = __builtin_amdgcn_mfma_f32_16x16x32_bf16(
                    al[i], bh2[j], acc[i][j], 0, 0, 0);
                acc[i][j] = __builtin_amdgcn_mfma_f32_16x16x32_bf16(
                    ah[i], bl2[j], acc[i][j], 0, 0, 0);
                acc[i][j] = __builtin_amdgcn_mfma_f32_16x16x32_bf16(
                    ah[i], bh2[j], acc[i][j], 0, 0, 0);
            }
        __syncthreads();
    }

    const int colq = colBase + wc * 32 + rr;
    const int rq0  = rowBase + wr * 64 + (lane >> 4) * 4;
    #pragma unroll
    for (int j = 0; j < 2; ++j) {
        const int col = colq + j * 16;
        const float bi = bias[col];
        #pragma unroll
        for (int i = 0; i < 4; ++i) {
            #pragma unroll
            for (int r = 0; r < 4; ++r) {
                const int row = rq0 + i * 16 + r;
                float v = acc[i][j][r] + bi;
                if constexpr (EPI == 1) {      // embed epilogue
                    float xv = tmask[row] ? mtok[col] : v;
                    out[(size_t)row * NO + col] = xv
                        + hemb[(size_t)hids[row] * DD + col]
                        + wemb[(size_t)wids[row] * DD + col];
                } else {
                    out[(size_t)row * NO + col] = v;
                }
            }
        }
    }
}

// ---------------------------------------------------------------------------
// bf16 MFMA GEMM: C[M x NO] = A[M x K] @ W[K x NO]
// Tile 128x128, BK=32, 4 waves (2x2), 64x64/wave = 4x4 frags of 16x16x32.
// EPI: 0 = bias -> bf16 out ; 3 = gelu -> bf16  (used for qkv, fc1)
// ---------------------------------------------------------------------------
template <int EPI>
__global__ __launch_bounds__(256) void bgemm_k(
    const unsigned short* __restrict__ A, const unsigned short* __restrict__ Wt,
    const float* __restrict__ bias, void* __restrict__ out,
    int K, int NO, const float* __restrict__ ls)
{
    __shared__ unsigned short As[128][40];
    __shared__ unsigned short Bs[128][40];

    const int tid  = threadIdx.x;
    const int lane = tid & 63;
    const int wave = tid >> 6;
    const int wr = wave >> 1, wc = wave & 1;
    const int rowBase = blockIdx.x * 128;
    const int colBase = blockIdx.y * 128;
    const int rr = lane & 15;
    const int kr = (lane >> 4) * 8;

    f32x4 acc[4][4] = {};

    for (int k0 = 0; k0 < K; k0 += 32) {
        #pragma unroll
        for (int i = 0; i < 2; ++i) {
            int s   = tid + i * 256;       // 0..511
            int row = s >> 2;              // 0..127
            int seg = (s & 3) * 8;         // bf16 offset 0,8,16,24
            *(short8*)&As[row][seg] =
                *(const short8*)&A[(size_t)(rowBase + row) * K + k0 + seg];
            *(short8*)&Bs[row][seg] =
                *(const short8*)&Wt[(size_t)(colBase + row) * K + k0 + seg];
        }
        __syncthreads();

        short8 af[4], bfr[4];
        #pragma unroll
        for (int i = 0; i < 4; ++i)
            af[i] = *(const short8*)&As[wr * 64 + i * 16 + rr][kr];
        #pragma unroll
        for (int j = 0; j < 4; ++j)
            bfr[j] = *(const short8*)&Bs[wc * 64 + j * 16 + rr][kr];
        #pragma unroll
        for (int i = 0; i < 4; ++i)
            #pragma unroll
            for (int j = 0; j < 4; ++j)
                acc[i][j] = __builtin_amdgcn_mfma_f32_16x16x32_bf16(
                    af[i], bfr[j], acc[i][j], 0, 0, 0);
        __syncthreads();
    }

    const int colq = colBase + wc * 64 + rr;
    const int rq0  = rowBase + wr * 64 + (lane >> 4) * 4;
    #pragma unroll
    for (int j = 0; j < 4; ++j) {
        const int col = colq + j * 16;
        const float bi = bias[col];
        #pragma unroll
        for (int i = 0; i < 4; ++i) {
            #pragma unroll
            for (int r = 0; r < 4; ++r) {
                const int row = rq0 + i * 16 + r;
                float v = acc[i][j][r] + bi;
                if constexpr (EPI == 0) {
                    ((unsigned short*)out)[(size_t)row * NO + col] = f2b(v);
                } else {  // gelu (exact) -> bf16
                    float g = 0.5f * v * (1.0f + erff(v * 0.70710678118654752f));
                    ((unsigned short*)out)[(size_t)row * NO + col] = f2b(g);
                }
            }
        }
    }
}

// ---------------------------------------------------------------------------
// 64x64-tile bf16 GEMM for small-N residual outputs (proj, fc2):
// grid = (M/64)x(N/64) = 768 blocks (3/CU) vs 192 at 128^2 — beats the
// k-loop latency via block co-residency (m114 overlap). No atomics
// (round-12 lesson: split-K atomicAdd cost 4x write traffic, net wash).
// Each output element owned by one block -> plain RMW: h += ls*(acc+bias).
// ---------------------------------------------------------------------------
__global__ __launch_bounds__(256) void bgemm64_k(
    const unsigned short* __restrict__ A, const unsigned short* __restrict__ Wt,
    const float* __restrict__ bias, float* __restrict__ h,
    int K, int NO, const float* __restrict__ ls)
{
    __shared__ unsigned short As[64][40];
    __shared__ unsigned short Bs[64][40];

    const int tid  = threadIdx.x;
    const int lane = tid & 63;
    const int wave = tid >> 6;
    const int wr = wave >> 1, wc = wave & 1;     // 2x2 waves, 32x32 each
    const int rowBase = blockIdx.x * 64;
    const int colBase = blockIdx.y * 64;
    const int rr = lane & 15;
    const int kr = (lane >> 4) * 8;

    f32x4 acc[2][2] = {};

    for (int k0 = 0; k0 < K; k0 += 32) {
        {
            int row = tid >> 2;            // 0..63
            int seg = (tid & 3) * 8;
            *(short8*)&As[row][seg] =
                *(const short8*)&A[(size_t)(rowBase + row) * K + k0 + seg];
            *(short8*)&Bs[row][seg] =
                *(const short8*)&Wt[(size_t)(colBase + row) * K + k0 + seg];
        }
        __syncthreads();

        short8 af[2], bfr[2];
        #pragma unroll
        for (int i = 0; i < 2; ++i)
            af[i] = *(const short8*)&As[wr * 32 + i * 16 + rr][kr];
        #pragma unroll
        for (int j = 0; j < 2; ++j)
            bfr[j] = *(const short8*)&Bs[wc * 32 + j * 16 + rr][kr];
        #pragma unroll
        for (int i = 0; i < 2; ++i)
            #pragma unroll
            for (int j = 0; j < 2; ++j)
                acc[i][j] = __builtin_amdgcn_mfma_f32_16x16x32_bf16(
                    af[i], bfr[j], acc[i][j], 0, 0, 0);
        __syncthreads();
    }

    const int colq = colBase + wc * 32 + rr;
    const int rq0  = rowBase + wr * 32 + (lane >> 4) * 4;
    #pragma unroll
    for (int j = 0; j < 2; ++j) {
        const int col = colq + j * 16;
        const float bi = bias[col];
        const float lsv = ls[col];
        #pragma unroll
        for (int i = 0; i < 2; ++i) {
            #pragma unroll
            for (int r = 0; r < 4; ++r) {
                const int row = rq0 + i * 16 + r;
                float* hp = &h[(size_t)row * NO + col];
                *hp += lsv * (acc[i][j][r] + bi);
            }
        }
    }
}

// ---------------------------------------------------------------------------
// LayerNorm: one wave per row, float2-vectorized.
// OUT: 1 = bf16 out ; 2 = bf16 hi/lo pair out (for the split GEMM input)
// ---------------------------------------------------------------------------
template <int OUT>
__global__ __launch_bounds__(256) void ln_k(
    const float* __restrict__ X, const float* __restrict__ w,
    const float* __restrict__ b, void* __restrict__ Y, void* __restrict__ Yl)
{
    int row  = blockIdx.x * 4 + (threadIdx.x >> 6);
    int lane = threadIdx.x & 63;
    const float* xr = X + (size_t)row * DD;

    float2 x2[3];
    #pragma unroll
    for (int j = 0; j < 3; ++j)
        x2[j] = *(const float2*)&xr[2 * (lane + 64 * j)];

    float s = 0.f;
    #pragma unroll
    for (int j = 0; j < 3; ++j) s += x2[j].x + x2[j].y;
    #pragma unroll
    for (int off = 32; off > 0; off >>= 1) s += __shfl_xor(s, off);
    float mu = s * (1.0f / 384.0f);

    float v = 0.f;
    #pragma unroll
    for (int j = 0; j < 3; ++j) {
        float d0 = x2[j].x - mu, d1 = x2[j].y - mu;
        v += d0 * d0 + d1 * d1;
    }
    #pragma unroll
    for (int off = 32; off > 0; off >>= 1) v += __shfl_xor(v, off);
    float rstd = rsqrtf(v * (1.0f / 384.0f) + EPSF);

    #pragma unroll
    for (int j = 0; j < 3; ++j) {
        int c = 2 * (lane + 64 * j);
        float2 w2 = *(const float2*)&w[c];
        float2 b2 = *(const float2*)&b[c];
        float y0 = (x2[j].x - mu) * rstd * w2.x + b2.x;
        float y1 = (x2[j].y - mu) * rstd * w2.y + b2.y;
        unsigned short h0 = f2b(y0), h1 = f2b(y1);
        *(ushort2*)&((unsigned short*)Y)[(size_t)row * DD + c] = make_ushort2(h0, h1);
        if constexpr (OUT == 2) {
            unsigned short l0 = f2b(y0 - b2f(h0)), l1 = f2b(y1 - b2f(h1));
            *(ushort2*)&((unsigned short*)Yl)[(size_t)row * DD + c] = make_ushort2(l0, l1);
        }
    }
}

// ---------------------------------------------------------------------------
// MFMA flash attention with block-diagonal tile skipping (see round-7 notes).
// ---------------------------------------------------------------------------
__global__ __launch_bounds__(256) void attn_mfma_k(
    const unsigned short* __restrict__ qkv, const int* __restrict__ sids,
    const int* __restrict__ smask, const int2* __restrict__ kmm,
    const unsigned short* __restrict__ vmean, unsigned short* __restrict__ out)
{
    __shared__ unsigned short Vt[32][72];     // [d][key], pad 64->72
    __shared__ int ck[64];
    __shared__ unsigned short P[4][16][64];   // per-wave P tile (XOR-swizzled cols)
    __shared__ int qmn[4], qmx[4];

    const int tid  = threadIdx.x;
    const int lane = tid & 63;
    const int wave = tid >> 6;
    const int g = lane >> 4;                  // 0..3
    const int c = lane & 15;

    const int bh = blockIdx.x >> 4;           // 16 q-tiles per (b,h)
    const int qt = blockIdx.x & 15;
    const int b = bh / HH, h = bh % HH;
    const int q0w = qt * 64 + wave * 16;
    const size_t qrow = 3 * DD;               // 1152

    const short8 qf = *(const short8*)&qkv[(size_t)(b * NN + q0w + c) * qrow + h * HDD + g * 8];

    int cq[4];
    #pragma unroll
    for (int r = 0; r < 4; ++r) {
        int qq = b * NN + q0w + 4 * g + r;
        cq[r] = smask[qq] ? -2 : sids[qq];
    }

    {
        int lmin = 0x7fffffff, lmax = (int)0x80000000;
        #pragma unroll
        for (int r = 0; r < 4; ++r) {
            if (cq[r] != -2) { lmin = min(lmin, cq[r]); lmax = max(lmax, cq[r]); }
        }
        #pragma unroll
        for (int off = 32; off; off >>= 1) {
            lmin = min(lmin, __shfl_xor(lmin, off));
            lmax = max(lmax, __shfl_xor(lmax, off));
        }
        if (lane == 0) { qmn[wave] = lmin; qmx[wave] = lmax; }
    }
    __syncthreads();
    int qminb = min(min(qmn[0], qmn[1]), min(qmn[2], qmn[3]));
    int qmaxb = max(max(qmx[0], qmx[1]), max(qmx[2], qmx[3]));

    float m[4] = {-INFINITY, -INFINITY, -INFINITY, -INFINITY};
    float l[4] = {};
    f32x4 o[2] = {};
    const f32x4 zero = {};
    const float scale = 0.17677669529663687f; // HD^-0.5
    const float FMIN = -3.402823466e38f;

    for (int kt = 0; kt < NN / 64; ++kt) {
        const int2 kr2 = kmm[(b << 4) + kt];
        if (kr2.x > qmaxb || kr2.y < qminb) continue;   // block-uniform skip

        const int kb = kt * 64;
        {
            int key = tid & 63;
            int d8  = (tid >> 6) * 8;
            short8 v = *(const short8*)&qkv[(size_t)(b * NN + kb + key) * qrow + 2 * DD + h * HDD + d8];
            #pragma unroll
            for (int e = 0; e < 8; ++e)
                Vt[d8 + e][key] = (unsigned short)v[e];
            if (tid < 64) {
                int kk = b * NN + kb + tid;
                ck[tid] = smask[kk] ? -1 : sids[kk];
            }
        }
        __syncthreads();

        f32x4 s4[4];
        #pragma unroll
        for (int j = 0; j < 4; ++j) {
            short8 kf = *(const short8*)&qkv[(size_t)(b * NN + kb + 16 * j + c) * qrow + DD + h * HDD + g * 8];
            s4[j] = __builtin_amdgcn_mfma_f32_16x16x32_bf16(qf, kf, zero, 0, 0, 0);
        }

        float pm[4] = {FMIN, FMIN, FMIN, FMIN};
        #pragma unroll
        for (int j = 0; j < 4; ++j) {
            const int ckj = ck[16 * j + c];
            #pragma unroll
            for (int r = 0; r < 4; ++r) {
                float sv = (cq[r] != ckj) ? FMIN : s4[j][r] * scale;
                s4[j][r] = sv;
                pm[r] = fmaxf(pm[r], sv);
            }
        }
        #pragma unroll
        for (int off = 1; off < 16; off <<= 1)
            #pragma unroll
            for (int r = 0; r < 4; ++r)
                pm[r] = fmaxf(pm[r], __shfl_xor(pm[r], off));

        float fac[4], psum[4];
        #pragma unroll
        for (int r = 0; r < 4; ++r) {
            float mn = fmaxf(m[r], pm[r]);
            fac[r] = __expf(m[r] - mn);
            m[r] = mn;
            psum[r] = 0.f;
        }
        #pragma unroll
        for (int j = 0; j < 4; ++j) {
            #pragma unroll
            for (int r = 0; r < 4; ++r) {
                float p = __expf(s4[j][r] - m[r]);
                psum[r] += p;
                int row  = 4 * g + r;
                int colb = (2 * (16 * j + c)) ^ ((row & 7) << 4);
                *(unsigned short*)((char*)&P[wave][row][0] + colb) = f2b(p);
            }
        }
        #pragma unroll
        for (int off = 1; off < 16; off <<= 1)
            #pragma unroll
            for (int r = 0; r < 4; ++r)
                psum[r] += __shfl_xor(psum[r], off);
        #pragma unroll
        for (int r = 0; r < 4; ++r) l[r] = l[r] * fac[r] + psum[r];

        #pragma unroll
        for (int dc = 0; dc < 2; ++dc)
            #pragma unroll
            for (int r = 0; r < 4; ++r)
                o[dc][r] *= fac[r];

        #pragma unroll
        for (int kc = 0; kc < 2; ++kc) {
            int colb = (2 * (kc * 32 + g * 8)) ^ ((c & 7) << 4);
            short8 pf = *(const short8*)((char*)&P[wave][c][0] + colb);
            #pragma unroll
            for (int dc = 0; dc < 2; ++dc) {
                short8 vf = *(const short8*)&Vt[dc * 16 + c][kc * 32 + g * 8];
                o[dc] = __builtin_amdgcn_mfma_f32_16x16x32_bf16(pf, vf, o[dc], 0, 0, 0);
            }
        }
        __syncthreads();
    }

    #pragma unroll
    for (int r = 0; r < 4; ++r) {
        unsigned short* op = &out[(size_t)(b * NN + q0w + 4 * g + r) * DD + h * HDD];
        if (cq[r] == -2) {
            #pragma unroll
            for (int dc = 0; dc < 2; ++dc)
                op[dc * 16 + c] = vmean[bh * HDD + dc * 16 + c];
        } else {
            const float inv = 1.0f / l[r];
            #pragma unroll
            for (int dc = 0; dc < 2; ++dc)
                op[dc * 16 + c] = f2b(o[dc][r] * inv);
        }
    }
}

// ---------------------------------------------------------------------------
extern "C" void kernel_launch(void* const* d_in, const int* in_sizes, int n_in,
                              void* d_out, int out_size, void* d_ws, size_t ws_size,
                              hipStream_t stream)
{
    const float* x        = (const float*)d_in[0];
    const int*   hids     = (const int*)d_in[1];
    const int*   wids     = (const int*)d_in[2];
    const void*  tmask_rw = d_in[3];
    const int*   sids     = (const int*)d_in[4];
    const void*  smask_rw = d_in[5];
    const float* embed_w  = (const float*)d_in[7];
    const float* embed_b  = (const float*)d_in[8];
    const float* h_embed  = (const float*)d_in[9];
    const float* w_embed  = (const float*)d_in[10];
    const float* mtok     = (const float*)d_in[11];
    const float* norm1_w  = (const float*)d_in[12];
    const float* norm1_b  = (const float*)d_in[13];
    const float* ls1      = (const float*)d_in[14];
    const float* qkv_w    = (const float*)d_in[15];
    const float* qkv_b    = (const float*)d_in[16];
    const float* proj_w   = (const float*)d_in[17];
    const float* proj_b   = (const float*)d_in[18];
    const float* norm2_w  = (const float*)d_in[19];
    const float* norm2_b  = (const float*)d_in[20];
    const float* fc1_w    = (const float*)d_in[21];
    const float* fc1_b    = (const float*)d_in[22];
    const float* fc2_w    = (const float*)d_in[23];
    const float* fc2_b    = (const float*)d_in[24];
    const float* ls2      = (const float*)d_in[25];
    const float* pnorm_w  = (const float*)d_in[26];
    const float* pnorm_b  = (const float*)d_in[27];
    const float* pproj_w  = (const float*)d_in[28];
    const float* pproj_b  = (const float*)d_in[29];

    const size_t MD = (size_t)MM * DD;
    float*          h    = (float*)d_ws;
    unsigned short* zb   = (unsigned short*)(h + MD);
    unsigned short* hid  = zb + MD;                 // 4*MD ushorts
    unsigned short* qkvb = hid;                     // alias (disjoint liveness)
    unsigned short* zfh  = hid;                     // alias: pnorm hi (after fc2 done)
    unsigned short* zfl  = hid + MD;                // alias: pnorm lo
    const size_t xsz = (size_t)MM * DIN;            // 6.29M
    unsigned short* xh = hid;                       // alias: dead before qkv bgemm
    unsigned short* xl = hid + xsz;
    unsigned short* wT   = hid + 4 * MD;
    const size_t qkvTsz  = (size_t)LL * 3 * DD * DD;
    const size_t projTsz = (size_t)LL * DD * DD;
    const size_t fc1Tsz  = (size_t)LL * DD * 4 * DD;
    unsigned short* qkvT = wT;
    unsigned short* projT = qkvT + qkvTsz;
    unsigned short* fc1T  = projT + projTsz;
    unsigned short* fc2T  = fc1T + fc1Tsz;
    int* tm32 = (int*)(fc2T + fc1Tsz);
    int* sm32 = tm32 + MM;
    unsigned short* vmean = (unsigned short*)(sm32 + MM);   // 96*32 bf16
    int2* kmm = (int2*)(vmean + BB * HH * HDD);             // 128 int2
    const size_t ewsz = (size_t)DIN * DD;                   // 294912
    unsigned short* ewT_hi = (unsigned short*)(kmm + BB * 16);
    unsigned short* ewT_lo = ewT_hi + ewsz;
    unsigned short* pwT_hi = ewT_lo + ewsz;
    unsigned short* pwT_lo = pwT_hi + ewsz;

    cvt_mask_k<<<1, 1024, 0, stream>>>(tmask_rw, MM, tm32);
    cvt_mask_k<<<1, 1024, 0, stream>>>(smask_rw, MM, sm32);
    kminmax_k<<<BB * 16, 64, 0, stream>>>(sids, sm32, kmm);

    dim3 t256(256);
    tcast_k<<<dim3(DD/32, 3*DD/32, LL), t256, 0, stream>>>(qkv_w, qkvT, DD, 3*DD);
    tcast_k<<<dim3(DD/32, DD/32,   LL), t256, 0, stream>>>(proj_w, projT, DD, DD);
    tcast_k<<<dim3(DD/32, 4*DD/32, LL), t256, 0, stream>>>(fc1_w, fc1T, DD, 4*DD);
    tcast_k<<<dim3(4*DD/32, DD/32, LL), t256, 0, stream>>>(fc2_w, fc2T, 4*DD, DD);
    tcast2_k<<<dim3(DIN/32, DD/32), t256, 0, stream>>>(embed_w, ewT_hi, ewT_lo, DIN, DD);
    tcast2_k<<<dim3(DD/32, DIN/32), t256, 0, stream>>>(pproj_w, pwT_hi, pwT_lo, DD, DIN);
    split_k<<<2048, t256, 0, stream>>>(x, xh, xl, (int)(xsz / 4));

    sgemm_k<1><<<dim3(MM/128, DD/64), t256, 0, stream>>>(
        xh, xl, ewT_hi, ewT_lo, embed_b, h, DIN, DD, tm32, hids, wids, mtok, h_embed, w_embed);

    for (int i = 0; i < LL; ++i) {
        ln_k<1><<<MM/4, t256, 0, stream>>>(h, norm1_w + i*DD, norm1_b + i*DD, zb, nullptr);
        bgemm_k<0><<<dim3(MM/128, 3*DD/128), t256, 0, stream>>>(
            zb, qkvT + (size_t)i*3*DD*DD, qkv_b + i*3*DD, qkvb, DD, 3*DD, nullptr);
        vmean_k<<<BB * HH, t256, 0, stream>>>(qkvb, vmean);
        attn_mfma_k<<<dim3(BB*HH*(NN/64)), t256, 0, stream>>>(
            qkvb, sids, sm32, kmm, vmean, zb);
        // proj: 64x64 tile -> 768 blocks (was 192, latency-bound)
        bgemm64_k<<<dim3(MM/64, DD/64), t256, 0, stream>>>(
            zb, projT + (size_t)i*DD*DD, proj_b + i*DD, h, DD, DD, ls1 + i*DD);
        ln_k<1><<<MM/4, t256, 0, stream>>>(h, norm2_w + i*DD, norm2_b + i*DD, zb, nullptr);
        bgemm_k<3><<<dim3(MM/128, 4*DD/128), t256, 0, stream>>>(
            zb, fc1T + (size_t)i*DD*4*DD, fc1_b + i*4*DD, hid, DD, 4*DD, nullptr);
        // fc2: 64x64 tile -> 768 blocks (was 192; round-12 split-K atomics failed)
        bgemm64_k<<<dim3(MM/64, DD/64), t256, 0, stream>>>(
            hid, fc2T + (size_t)i*4*DD*DD, fc2_b + i*DD, h, 4*DD, DD, ls2 + i*DD);
    }

    ln_k<2><<<MM/4, t256, 0, stream>>>(h, pnorm_w, pnorm_b, zfh, zfl);
    sgemm_k<0><<<dim3(MM/128, DIN/64), t256, 0, stream>>>(
        zfh, zfl, pwT_hi, pwT_lo, pproj_b, (float*)d_out, DD, DIN,
        nullptr, nullptr, nullptr, nullptr, nullptr, nullptr);
}